// Round 10
// baseline (109.867 us; speedup 1.0000x reference)
//
#include <hip/hip_runtime.h>
#include <hip/hip_bf16.h>
#include <stdint.h>

typedef unsigned short ushort_t;
typedef __attribute__((ext_vector_type(4))) float f32x4;
typedef __attribute__((ext_vector_type(8))) short short8;

#define SS 2048
#define ROWS 4096      // B*S
#define EPS 1e-5f

__device__ __forceinline__ unsigned short f2bf(float f) {
  unsigned int u = __float_as_uint(f);
  u += 0x7FFF + ((u >> 16) & 1);   // round-to-nearest-even
  return (unsigned short)(u >> 16);
}
__device__ __forceinline__ float bf2f(short s) {
  return __uint_as_float(((unsigned int)(unsigned short)s) << 16);
}

#define GLDS16(g, l)                                                        \
  __builtin_amdgcn_global_load_lds((__attribute__((address_space(1))) void*)(g), \
                                   (__attribute__((address_space(3))) void*)(l), 16, 0, 0)

// ---------------- fused fp32 -> bf16 convert for x, W1 ----------------
__global__ __launch_bounds__(256) void f2b2_kernel(const float* __restrict__ a,
                                                   ushort_t* __restrict__ oa, int n4a,
                                                   const float* __restrict__ b,
                                                   ushort_t* __restrict__ ob, int n4b) {
  const int stride = gridDim.x * blockDim.x;
  const int total = n4a + n4b;
  for (int i = blockIdx.x * blockDim.x + threadIdx.x; i < total; i += stride) {
    const float4 v = (i < n4a) ? reinterpret_cast<const float4*>(a)[i]
                               : reinterpret_cast<const float4*>(b)[i - n4a];
    ushort4 o;
    o.x = f2bf(v.x); o.y = f2bf(v.y); o.z = f2bf(v.z); o.w = f2bf(v.w);
    if (i < n4a) reinterpret_cast<ushort4*>(oa)[i] = o;
    else         reinterpret_cast<ushort4*>(ob)[i - n4a] = o;
  }
}

// ---------------- GEMM1: qkv = x @ W1^T + b1 (bf16 out), pipelined ----------------
// M=4096 N=3072 K=1024. BM=256 BN=192 BK=32, 512 thr (8 waves: 2M x 4N),
// grid 16x16 = 256 blocks = 1/CU. 4 LDS buffers (112KB), prefetch depth 3,
// counted vmcnt (never 0 in main loop), raw s_barrier (1/K-tile), setprio,
// XOR swizzle byte^=((row>>1)&3)<<4 (2-way conflicts). Plain block mapping.
#define MF(d, va, vb) d = __builtin_amdgcn_mfma_f32_16x16x32_bf16(va, vb, d, 0, 0, 0)
#define LD8(p) (*reinterpret_cast<const short8*>(p))

__global__ __launch_bounds__(512, 2) void gemm1_pipe(const ushort_t* __restrict__ A,
                                                     const ushort_t* __restrict__ B,
                                                     const float* __restrict__ bias,
                                                     ushort_t* __restrict__ C) {
  __shared__ __align__(16) ushort_t lds[4 * 14336];   // [buf][A:8192 | B:6144] ushorts
  const int tid = threadIdx.x;
  const int wid = tid >> 6, lane = tid & 63;
  const int bm = blockIdx.x * 256, bn = blockIdx.y * 192;
  const int wm = wid >> 2, wn = wid & 3;

  const int srow = lane >> 2;                                   // row in chunk
  const int scol = ((lane & 3) ^ ((lane >> 3) & 3)) * 8;        // swizzled 16B slot
  const int widb = (wid < 6) ? wid : 0;
  const ushort_t* gA0 = A + (size_t)(bm + wid * 16 + srow) * 1024 + scol;
  const ushort_t* gA1 = A + (size_t)(bm + (8 + wid) * 16 + srow) * 1024 + scol;
  const ushort_t* gB0 = B + (size_t)(bn + widb * 16 + srow) * 1024 + scol;
  const ushort_t* gB1 = B + (size_t)(bn + (6 + widb) * 16 + srow) * 1024 + scol;

  const int lf = lane & 15, kf = lane >> 4;
  const int flip = ((lane >> 1) & 3) << 4;   // byte XOR from row bits 1,2
  const int aBase = (((wm * 128 + lf) * 64 + kf * 16) ^ flip) >> 1;
  const int bBase = ((((wn * 48 + lf) * 64 + kf * 16) ^ flip) >> 1) + 8192;

  f32x4 acc[8][3] = {};

#define STAGE_A(t)                                                           \
  { ushort_t* d = lds + (((t) & 3) * 14336);                                 \
    GLDS16(gA0 + (t) * 32, d + wid * 512);                                   \
    GLDS16(gA1 + (t) * 32, d + (8 + wid) * 512); }
#define STAGE_B(t)                                                           \
  if (wid < 6) { ushort_t* d = lds + (((t) & 3) * 14336) + 8192;             \
    GLDS16(gB0 + (t) * 32, d + wid * 512);                                   \
    GLDS16(gB1 + (t) * 32, d + (6 + wid) * 512); }

  STAGE_A(0) STAGE_B(0)
  STAGE_A(1) STAGE_B(1)
  STAGE_A(2) STAGE_B(2)
  if (wid < 6) { asm volatile("s_waitcnt vmcnt(8)" ::: "memory"); }
  else         { asm volatile("s_waitcnt vmcnt(4)" ::: "memory"); }
  __builtin_amdgcn_s_barrier();
  __builtin_amdgcn_sched_barrier(0);

#define K_TILE(t, DO_STAGE, VM6, VM2)                                        \
  { const ushort_t* Lb = lds + (((t) & 3) * 14336);                          \
    short8 bv0 = LD8(Lb + bBase);                                            \
    short8 bv1 = LD8(Lb + bBase + 512);                                      \
    short8 bv2 = LD8(Lb + bBase + 1024);                                     \
    short8 a0 = LD8(Lb + aBase);                                             \
    short8 a1 = LD8(Lb + aBase + 512);                                       \
    short8 a2 = LD8(Lb + aBase + 1024);                                      \
    short8 a3 = LD8(Lb + aBase + 1536);                                      \
    if (DO_STAGE) STAGE_A((t) + 3)                                           \
    __builtin_amdgcn_s_setprio(1);                                           \
    MF(acc[0][0], a0, bv0); MF(acc[1][0], a1, bv0);                          \
    MF(acc[0][1], a0, bv1); MF(acc[1][1], a1, bv1);                          \
    MF(acc[0][2], a0, bv2); MF(acc[1][2], a1, bv2);                          \
    MF(acc[2][0], a2, bv0); MF(acc[3][0], a3, bv0);                          \
    MF(acc[2][1], a2, bv1); MF(acc[3][1], a3, bv1);                          \
    MF(acc[2][2], a2, bv2); MF(acc[3][2], a3, bv2);                          \
    __builtin_amdgcn_s_setprio(0);                                           \
    a0 = LD8(Lb + aBase + 2048);                                             \
    a1 = LD8(Lb + aBase + 2560);                                             \
    a2 = LD8(Lb + aBase + 3072);                                             \
    a3 = LD8(Lb + aBase + 3584);                                             \
    if (DO_STAGE) STAGE_B((t) + 3)                                           \
    __builtin_amdgcn_s_setprio(1);                                           \
    MF(acc[4][0], a0, bv0); MF(acc[5][0], a1, bv0);                          \
    MF(acc[4][1], a0, bv1); MF(acc[5][1], a1, bv1);                          \
    MF(acc[4][2], a0, bv2); MF(acc[5][2], a1, bv2);                          \
    MF(acc[6][0], a2, bv0); MF(acc[7][0], a3, bv0);                          \
    MF(acc[6][1], a2, bv1); MF(acc[7][1], a3, bv1);                          \
    MF(acc[6][2], a2, bv2); MF(acc[7][2], a3, bv2);                          \
    __builtin_amdgcn_s_setprio(0);                                           \
    __builtin_amdgcn_sched_barrier(0);                                       \
    if (wid < 6) { asm volatile("s_waitcnt vmcnt(" #VM6 ")" ::: "memory"); } \
    else         { asm volatile("s_waitcnt vmcnt(" #VM2 ")" ::: "memory"); } \
    __builtin_amdgcn_s_barrier();                                            \
    __builtin_amdgcn_sched_barrier(0); }

#pragma unroll 1
  for (int t = 0; t < 29; ++t) K_TILE(t, 1, 8, 4)
  K_TILE(29, 0, 4, 2)
  K_TILE(30, 0, 0, 0)
  K_TILE(31, 0, 0, 0)

  const int crow = bm + wm * 128 + (lane >> 4) * 4;
  const int ccol = bn + wn * 48 + (lane & 15);
#pragma unroll
  for (int m = 0; m < 8; ++m)
#pragma unroll
    for (int n = 0; n < 3; ++n) {
      const int col = ccol + n * 16;
      const float bb = bias[col];
#pragma unroll
      for (int j = 0; j < 4; ++j)
        C[(size_t)(crow + m * 16 + j) * 3072 + col] = f2bf(acc[m][n][j] + bb);
    }
#undef K_TILE
#undef STAGE_A
#undef STAGE_B
}

// ---------------- GEMM3: out = Q @ M_b^T + bias2_b (fp32 out), pipelined ----------------
// M=4096 N=1024 K=1024. A = Q slice of qkvb (row stride 3072). BM=64 BN=128
// BK=32, 256 thr (4 waves: 2M x 2N), grid (64,8) = 512 blocks = 2/CU (48KB LDS).
// dualB: second M/bias2 copy for rows >= 2048 (batch 1).
__global__ __launch_bounds__(256, 2) void gemm3_pipe(const ushort_t* __restrict__ A,
                                                     const ushort_t* __restrict__ B,
                                                     const float* __restrict__ bias,
                                                     float* __restrict__ C) {
  __shared__ __align__(16) ushort_t lds[4 * 6144];   // [buf][A:2048 | B:4096] ushorts
  const int tid = threadIdx.x;
  const int wid = tid >> 6, lane = tid & 63;
  const int bm = blockIdx.x * 64, bn = blockIdx.y * 128;
  if (bm >= 2048) { B += (size_t)1024 * 1024; bias += 1024; }
  const int wm = wid >> 1, wn = wid & 1;

  const int srow = lane >> 2;
  const int scol = ((lane & 3) ^ ((lane >> 3) & 3)) * 8;
  const ushort_t* gA  = A + (size_t)(bm + wid * 16 + srow) * 3072 + scol;  // Q: stride 3072
  const ushort_t* gB0 = B + (size_t)(bn + wid * 16 + srow) * 1024 + scol;
  const ushort_t* gB1 = B + (size_t)(bn + (4 + wid) * 16 + srow) * 1024 + scol;

  const int lf = lane & 15, kf = lane >> 4;
  const int flip = ((lane >> 1) & 3) << 4;
  const int aBase = (((wm * 32 + lf) * 64 + kf * 16) ^ flip) >> 1;
  const int bBase = ((((wn * 64 + lf) * 64 + kf * 16) ^ flip) >> 1) + 2048;

  f32x4 acc[2][4] = {};

#define STAGE3(t)                                                            \
  { ushort_t* d = lds + (((t) & 3) * 6144);                                  \
    GLDS16(gA + (t) * 32, d + wid * 512);                                    \
    GLDS16(gB0 + (t) * 32, d + 2048 + wid * 512);                            \
    GLDS16(gB1 + (t) * 32, d + 2048 + (4 + wid) * 512); }

  STAGE3(0) STAGE3(1) STAGE3(2)
  asm volatile("s_waitcnt vmcnt(6)" ::: "memory");
  __builtin_amdgcn_s_barrier();
  __builtin_amdgcn_sched_barrier(0);

#define K_TILE3(t, DO_STAGE, VM)                                             \
  { const ushort_t* Lb = lds + (((t) & 3) * 6144);                           \
    short8 bv0 = LD8(Lb + bBase);                                            \
    short8 bv1 = LD8(Lb + bBase + 512);                                      \
    short8 bv2 = LD8(Lb + bBase + 1024);                                     \
    short8 bv3 = LD8(Lb + bBase + 1536);                                     \
    short8 a0 = LD8(Lb + aBase);                                             \
    short8 a1 = LD8(Lb + aBase + 512);                                       \
    if (DO_STAGE) STAGE3((t) + 3)                                            \
    __builtin_amdgcn_s_setprio(1);                                           \
    MF(acc[0][0], a0, bv0); MF(acc[1][0], a1, bv0);                          \
    MF(acc[0][1], a0, bv1); MF(acc[1][1], a1, bv1);                          \
    MF(acc[0][2], a0, bv2); MF(acc[1][2], a1, bv2);                          \
    MF(acc[0][3], a0, bv3); MF(acc[1][3], a1, bv3);                          \
    __builtin_amdgcn_s_setprio(0);                                           \
    __builtin_amdgcn_sched_barrier(0);                                       \
    asm volatile("s_waitcnt vmcnt(" #VM ")" ::: "memory");                   \
    __builtin_amdgcn_s_barrier();                                            \
    __builtin_amdgcn_sched_barrier(0); }

#pragma unroll 1
  for (int t = 0; t < 29; ++t) K_TILE3(t, 1, 6)
  K_TILE3(29, 0, 3)
  K_TILE3(30, 0, 0)
  K_TILE3(31, 0, 0)

  const int crow = bm + wm * 32 + (lane >> 4) * 4;
  const int ccol = bn + wn * 64 + lf;
#pragma unroll
  for (int m = 0; m < 2; ++m)
#pragma unroll
    for (int n = 0; n < 4; ++n) {
      const int col = ccol + n * 16;
      const float bb = bias[col];
#pragma unroll
      for (int j = 0; j < 4; ++j)
        C[(size_t)(crow + m * 16 + j) * 1024 + col] = acc[m][n][j] + bb;
    }
#undef K_TILE3
#undef STAGE3
}

// ---------------- partials per (b,h,chunk=256 rows): KV=K^T V, Qcov=Q^T Q, qsum ----------------
// grid = 64 bh * 8 chunks = 512 blocks (2/CU). 4 sequential 64-row LDS slabs.
__global__ __launch_bounds__(256) void kvq_partial(const ushort_t* __restrict__ qkvb,
                                                   float* __restrict__ KVp,
                                                   float* __restrict__ Qcovp,
                                                   float* __restrict__ qsump) {
  __shared__ float qt[2048], kt[2048], vt[2048];
  const int blk = blockIdx.x;
  const int bh = blk >> 3;
  const int ch = blk & 7;
  const int b = bh >> 5, h = bh & 31;
  const int tid = threadIdx.x;
  const int r = tid >> 2, cg = (tid & 3) * 8;
  const int d = tid & 31, eg = tid >> 5;
  float kv[4] = {0.f, 0.f, 0.f, 0.f};
  float qc[4] = {0.f, 0.f, 0.f, 0.f};
  float qs = 0.f;
  for (int slab = 0; slab < 4; ++slab) {
    const ushort_t* base = qkvb +
        (size_t)(b * SS + ch * 256 + slab * 64 + r) * 3072 + h * 32 + cg;
    const short8 q8 = LD8(base);
    const short8 k8 = LD8(base + 1024);
    const short8 v8 = LD8(base + 2048);
    if (slab) __syncthreads();      // protect prior slab's reads
#pragma unroll
    for (int i = 0; i < 8; ++i) {
      qt[r * 32 + cg + i] = bf2f(q8[i]);
      kt[r * 32 + cg + i] = bf2f(k8[i]);
      vt[r * 32 + cg + i] = bf2f(v8[i]);
    }
    __syncthreads();
#pragma unroll 4
    for (int ss = 0; ss < 64; ++ss) {
      const float vv = vt[ss * 32 + d];
      const float qd = qt[ss * 32 + d];
#pragma unroll
      for (int i = 0; i < 4; ++i) {
        kv[i] += kt[ss * 32 + eg * 4 + i] * vv;
        qc[i] += qt[ss * 32 + eg * 4 + i] * qd;
      }
    }
    if (tid < 32) {
      float s = 0.f;
      for (int ss = 0; ss < 64; ++ss) s += qt[ss * 32 + tid];
      qs += s;
    }
  }
  float* okv = KVp + ((size_t)bh * 8 + ch) * 1024 + (eg * 4) * 32 + d;
  float* oqc = Qcovp + ((size_t)bh * 8 + ch) * 1024 + (eg * 4) * 32 + d;
#pragma unroll
  for (int i = 0; i < 4; ++i) { okv[i * 32] = kv[i]; oqc[i * 32] = qc[i]; }
  if (tid < 32) qsump[((size_t)bh * 8 + ch) * 32 + tid] = qs;
}

// ---------------- reduce 8 partials per (b,h); stats via quadratic form ----------------
// E2 = sum_d KV[:,d]^T Qcov KV[:,d];  MS = sum_e qsum[e]*rowsum_e(KV)
__global__ __launch_bounds__(256) void kvq_reduce_stats(const float* __restrict__ KVp,
                                                        const float* __restrict__ Qcovp,
                                                        const float* __restrict__ qsump,
                                                        float* __restrict__ KV,
                                                        float2* __restrict__ stats) {
  __shared__ float kvs[1024], qcov[1024], qsums[32], red[16];
  const int bh = blockIdx.x;          // 64 blocks
  const int tid = threadIdx.x;        // 256 threads
  {
    const float* kbase = KVp + (size_t)bh * 8192 + tid * 4;
    const float* qbase = Qcovp + (size_t)bh * 8192 + tid * 4;
    float4 sk = make_float4(0.f, 0.f, 0.f, 0.f);
    float4 sq = make_float4(0.f, 0.f, 0.f, 0.f);
    for (int c = 0; c < 8; ++c) {
      const float4 k4 = *(const float4*)(kbase + c * 1024);
      const float4 q4 = *(const float4*)(qbase + c * 1024);
      sk.x += k4.x; sk.y += k4.y; sk.z += k4.z; sk.w += k4.w;
      sq.x += q4.x; sq.y += q4.y; sq.z += q4.z; sq.w += q4.w;
    }
    *(float4*)&kvs[tid * 4] = sk;
    *(float4*)&qcov[tid * 4] = sq;
    *(float4*)&KV[(size_t)bh * 1024 + tid * 4] = sk;
  }
  if (tid < 32) {
    float s = 0.f;
    for (int c = 0; c < 8; ++c) s += qsump[((size_t)bh * 8 + c) * 32 + tid];
    qsums[tid] = s;
  }
  __syncthreads();
  const int d = tid & 31, ig = tid >> 5;
  float e2p = 0.f;
#pragma unroll
  for (int ii = 0; ii < 4; ++ii) {
    const int i = ig * 4 + ii;
    float t = 0.f;
#pragma unroll
    for (int j = 0; j < 32; ++j) t += qcov[i * 32 + j] * kvs[j * 32 + d];
    e2p += kvs[i * 32 + d] * t;
  }
#pragma unroll
  for (int off = 32; off > 0; off >>= 1) e2p += __shfl_down(e2p, off);
  float mp = 0.f;
  if (tid < 32) {
    float rs = 0.f;
    for (int dd = 0; dd < 32; ++dd) rs += kvs[tid * 32 + ((dd + tid) & 31)];
    mp = rs * qsums[tid];
  }
#pragma unroll
  for (int off = 32; off > 0; off >>= 1) mp += __shfl_down(mp, off);
  const int wave = tid >> 6, lane = tid & 63;
  if (lane == 0) { red[wave] = e2p; red[8 + wave] = mp; }
  __syncthreads();
  if (tid == 0) {
    const float E2 = red[0] + red[1] + red[2] + red[3];
    const float MS = red[8] + red[9] + red[10] + red[11];
    const float mean = MS * (1.f / 65536.f);
    const float var = E2 * (1.f / 65536.f) - mean * mean;
    stats[bh] = make_float2(mean, rsqrtf(var + EPS));
  }
}

// ---------------- buildM: fold KV + groupnorm + W2 into one GEMM operand ----------------
// Ms[b][n][h*32+e] = bf16( sum_d  W2[n][h*32+d] * (rstd_bh*gw[h*32+d]) * KV_bh[e][d] )
// bias2[b][n]      = b2[n] + sum_c (gb[c] - mean_bh*rstd_bh*gw[c]) * W2[n][c]
// grid (64 n-blocks of 16 rows, 2 batches), 256 threads. KV fp32 in padded LDS
// (h-stride 1032 floats: breaks the 16-way bank conflict of stride-1024).
__global__ __launch_bounds__(256) void buildM_kernel(const float* __restrict__ W2,
                                                     const float* __restrict__ b2,
                                                     const float* __restrict__ gw,
                                                     const float* __restrict__ gb,
                                                     const float2* __restrict__ stats,
                                                     const float* __restrict__ KV,
                                                     ushort_t* __restrict__ Ms,
                                                     float* __restrict__ bias2) {
  __shared__ float kvl[32 * 1032];       // [h][e*32+d], padded (129 KB)
  __shared__ float sS[1024], sT[1024];
  const int b = blockIdx.y;
  const int tid = threadIdx.x;
  // stage KV_b (128 KB) into padded LDS
  for (int i = tid * 4; i < 32768; i += 1024) {
    const float4 v = *(const float4*)&KV[(size_t)b * 32768 + i];
    *(float4*)&kvl[i + (i >> 10) * 8] = v;
  }
  {
    const int c0 = tid * 4;
    const float2 st = stats[b * 32 + (c0 >> 5)];
    const float4 w = *(const float4*)&gw[c0];
    const float4 g = *(const float4*)&gb[c0];
    sS[c0]     = st.y * w.x;  sT[c0]     = g.x - st.x * st.y * w.x;
    sS[c0 + 1] = st.y * w.y;  sT[c0 + 1] = g.y - st.x * st.y * w.y;
    sS[c0 + 2] = st.y * w.z;  sT[c0 + 2] = g.z - st.x * st.y * w.z;
    sS[c0 + 3] = st.y * w.w;  sT[c0 + 3] = g.w - st.x * st.y * w.w;
  }
  __syncthreads();
  const int n = blockIdx.x * 16 + (tid >> 4);
  const int h0 = (tid & 15) * 2;        // this thread: heads h0, h0+1
  float pb = 0.f;
#pragma unroll
  for (int hh = 0; hh < 2; ++hh) {
    const int h = h0 + hh;
    float wt[32];
#pragma unroll
    for (int dq = 0; dq < 8; ++dq) {
      const int c = h * 32 + dq * 4;
      const float4 w4 = *(const float4*)&W2[(size_t)n * 1024 + c];
      wt[dq * 4]     = w4.x * sS[c];
      wt[dq * 4 + 1] = w4.y * sS[c + 1];
      wt[dq * 4 + 2] = w4.z * sS[c + 2];
      wt[dq * 4 + 3] = w4.w * sS[c + 3];
      pb += w4.x * sT[c] + w4.y * sT[c + 1] + w4.z * sT[c + 2] + w4.w * sT[c + 3];
    }
    const float* kr = &kvl[h * 1032];
    ushort_t* orow = Ms + (size_t)b * 1048576 + (size_t)n * 1024 + h * 32;
#pragma unroll 4
    for (int e = 0; e < 32; ++e) {
      float dot = 0.f;
#pragma unroll
      for (int dq = 0; dq < 8; ++dq) {
        const float4 k4 = *(const float4*)&kr[e * 32 + dq * 4];
        dot += wt[dq * 4] * k4.x + wt[dq * 4 + 1] * k4.y +
               wt[dq * 4 + 2] * k4.z + wt[dq * 4 + 3] * k4.w;
      }
      orow[e] = f2bf(dot);
    }
  }
  // reduce pb over the 16 threads sharing row n
#pragma unroll
  for (int off = 8; off > 0; off >>= 1) pb += __shfl_down(pb, off, 16);
  if ((tid & 15) == 0) bias2[b * 1024 + n] = b2[n] + pb;
}

extern "C" void kernel_launch(void* const* d_in, const int* in_sizes, int n_in,
                              void* d_out, int out_size, void* d_ws, size_t ws_size,
                              hipStream_t stream) {
  const float* x  = (const float*)d_in[0];
  const float* w1 = (const float*)d_in[1];
  const float* b1 = (const float*)d_in[2];
  const float* gw = (const float*)d_in[3];
  const float* gb = (const float*)d_in[4];
  const float* w2 = (const float*)d_in[5];
  const float* b2 = (const float*)d_in[6];
  float* out = (float*)d_out;

  char* ws = (char*)d_ws;
  ushort_t* Xb    = (ushort_t*)(ws);                 // 8 MB (dead after gemm1)
  float*    KVp   = (float*)(ws);                    // 2 MB, reuses Xb region
  ushort_t* W1b   = (ushort_t*)(ws + 8388608);       // 6 MB (dead after gemm1)
  float*    Qcovp = (float*)(ws + 8388608);          // 2 MB, reuses W1b region
  ushort_t* qkvb  = (ushort_t*)(ws + 16777216);      // 24 MB bf16
  ushort_t* Ms    = (ushort_t*)(ws + 41943040);      // 4 MB (2 batches x 1024x1024 bf16)
  float*    qsump = (float*)(ws + 52428800);         // 64 KB
  float*    KV    = (float*)(ws + 52690944);         // 256 KB
  float2*   stats = (float2*)(ws + 52953088);        // 512 B
  float*    bias2 = (float*)(ws + 52954112);         // 8 KB

  // 1. convert x, W1 to bf16
  f2b2_kernel<<<2048, 256, 0, stream>>>(x, Xb, ROWS * 1024 / 4, w1, W1b, 3072 * 1024 / 4);
  // 2. qkv = x @ Wqkv^T + b  (bf16 out) — pipelined GEMM
  gemm1_pipe<<<dim3(16, 16), 512, 0, stream>>>(Xb, W1b, b1, qkvb);
  // 3. per-(b,h,chunk=256) partials: KV = K^T V, Qcov = Q^T Q, qsum
  kvq_partial<<<512, 256, 0, stream>>>(qkvb, KVp, Qcovp, qsump);
  // 4. one reduce per (b,h) + groupnorm stats via quadratic form
  kvq_reduce_stats<<<64, 256, 0, stream>>>(KVp, Qcovp, qsump, KV, stats);
  // 5. fold KV + groupnorm + W2 into Ms, bias2 (per batch)
  buildM_kernel<<<dim3(64, 2), 256, 0, stream>>>(w2, b2, gw, gb, stats, KV, Ms, bias2);
  // 6. out = Q @ Ms^T + bias2 — pipelined GEMM (ctx/norm fully folded)
  gemm3_pipe<<<dim3(64, 8), 256, 0, stream>>>(qkvb, Ms, bias2, out);
}

// Round 11
// 88.216 us; speedup vs baseline: 1.2454x; 1.2454x over previous
//
#include <hip/hip_runtime.h>
#include <hip/hip_bf16.h>
#include <stdint.h>

typedef unsigned short ushort_t;
typedef __attribute__((ext_vector_type(4))) float f32x4;
typedef __attribute__((ext_vector_type(8))) short short8;

#define SS 2048
#define ROWS 4096      // B*S
#define EPS 1e-5f

__device__ __forceinline__ unsigned short f2bf(float f) {
  unsigned int u = __float_as_uint(f);
  u += 0x7FFF + ((u >> 16) & 1);   // round-to-nearest-even
  return (unsigned short)(u >> 16);
}
__device__ __forceinline__ float bf2f(short s) {
  return __uint_as_float(((unsigned int)(unsigned short)s) << 16);
}

#define GLDS16(g, l)                                                        \
  __builtin_amdgcn_global_load_lds((__attribute__((address_space(1))) void*)(g), \
                                   (__attribute__((address_space(3))) void*)(l), 16, 0, 0)

// ---------------- fused fp32 -> bf16 convert for x and W1 ----------------
__global__ __launch_bounds__(256) void f2b2_kernel(const float* __restrict__ a,
                                                   ushort_t* __restrict__ oa, int n4a,
                                                   const float* __restrict__ b,
                                                   ushort_t* __restrict__ ob, int n4b) {
  const int stride = gridDim.x * blockDim.x;
  const int total = n4a + n4b;
  for (int i = blockIdx.x * blockDim.x + threadIdx.x; i < total; i += stride) {
    const float4 v = (i < n4a) ? reinterpret_cast<const float4*>(a)[i]
                               : reinterpret_cast<const float4*>(b)[i - n4a];
    ushort4 o;
    o.x = f2bf(v.x); o.y = f2bf(v.y); o.z = f2bf(v.z); o.w = f2bf(v.w);
    if (i < n4a) reinterpret_cast<ushort4*>(oa)[i] = o;
    else         reinterpret_cast<ushort4*>(ob)[i - n4a] = o;
  }
}

// ---------------- GEMM1: qkv = x @ W1^T + b1 (bf16 out), pipelined ----------------
// M=4096 N=3072 K=1024. BM=256 BN=192 BK=32, 512 thr (8 waves: 2M x 4N),
// grid 16x16 = 256 blocks = 1/CU. 4 LDS buffers (112KB), prefetch depth 3,
// counted vmcnt (never 0 in main loop), raw s_barrier (1/K-tile), setprio,
// XOR swizzle byte^=((row>>1)&3)<<4 (2-way conflicts). Plain block mapping
// (XCD swizzle measured -4us in r7: 5MB/XCD working set > 4MiB L2).
#define MF(d, va, vb) d = __builtin_amdgcn_mfma_f32_16x16x32_bf16(va, vb, d, 0, 0, 0)
#define LD8(p) (*reinterpret_cast<const short8*>(p))

__global__ __launch_bounds__(512, 2) void gemm1_pipe(const ushort_t* __restrict__ A,
                                                     const ushort_t* __restrict__ B,
                                                     const float* __restrict__ bias,
                                                     ushort_t* __restrict__ C) {
  __shared__ __align__(16) ushort_t lds[4 * 14336];   // [buf][A:8192 | B:6144] ushorts
  const int tid = threadIdx.x;
  const int wid = tid >> 6, lane = tid & 63;
  const int bm = blockIdx.x * 256, bn = blockIdx.y * 192;
  const int wm = wid >> 2, wn = wid & 3;

  const int srow = lane >> 2;                                   // row in chunk
  const int scol = ((lane & 3) ^ ((lane >> 3) & 3)) * 8;        // swizzled 16B slot
  const int widb = (wid < 6) ? wid : 0;
  const ushort_t* gA0 = A + (size_t)(bm + wid * 16 + srow) * 1024 + scol;
  const ushort_t* gA1 = A + (size_t)(bm + (8 + wid) * 16 + srow) * 1024 + scol;
  const ushort_t* gB0 = B + (size_t)(bn + widb * 16 + srow) * 1024 + scol;
  const ushort_t* gB1 = B + (size_t)(bn + (6 + widb) * 16 + srow) * 1024 + scol;

  const int lf = lane & 15, kf = lane >> 4;
  const int flip = ((lane >> 1) & 3) << 4;   // byte XOR from row bits 1,2
  const int aBase = (((wm * 128 + lf) * 64 + kf * 16) ^ flip) >> 1;
  const int bBase = ((((wn * 48 + lf) * 64 + kf * 16) ^ flip) >> 1) + 8192;

  f32x4 acc[8][3] = {};

#define STAGE_A(t)                                                           \
  { ushort_t* d = lds + (((t) & 3) * 14336);                                 \
    GLDS16(gA0 + (t) * 32, d + wid * 512);                                   \
    GLDS16(gA1 + (t) * 32, d + (8 + wid) * 512); }
#define STAGE_B(t)                                                           \
  if (wid < 6) { ushort_t* d = lds + (((t) & 3) * 14336) + 8192;             \
    GLDS16(gB0 + (t) * 32, d + wid * 512);                                   \
    GLDS16(gB1 + (t) * 32, d + (6 + wid) * 512); }

  STAGE_A(0) STAGE_B(0)
  STAGE_A(1) STAGE_B(1)
  STAGE_A(2) STAGE_B(2)
  if (wid < 6) { asm volatile("s_waitcnt vmcnt(8)" ::: "memory"); }
  else         { asm volatile("s_waitcnt vmcnt(4)" ::: "memory"); }
  __builtin_amdgcn_s_barrier();
  __builtin_amdgcn_sched_barrier(0);

#define K_TILE(t, DO_STAGE, VM6, VM2)                                        \
  { const ushort_t* Lb = lds + (((t) & 3) * 14336);                          \
    short8 bv0 = LD8(Lb + bBase);                                            \
    short8 bv1 = LD8(Lb + bBase + 512);                                      \
    short8 bv2 = LD8(Lb + bBase + 1024);                                     \
    short8 a0 = LD8(Lb + aBase);                                             \
    short8 a1 = LD8(Lb + aBase + 512);                                       \
    short8 a2 = LD8(Lb + aBase + 1024);                                      \
    short8 a3 = LD8(Lb + aBase + 1536);                                      \
    if (DO_STAGE) STAGE_A((t) + 3)                                           \
    __builtin_amdgcn_s_setprio(1);                                           \
    MF(acc[0][0], a0, bv0); MF(acc[1][0], a1, bv0);                          \
    MF(acc[0][1], a0, bv1); MF(acc[1][1], a1, bv1);                          \
    MF(acc[0][2], a0, bv2); MF(acc[1][2], a1, bv2);                          \
    MF(acc[2][0], a2, bv0); MF(acc[3][0], a3, bv0);                          \
    MF(acc[2][1], a2, bv1); MF(acc[3][1], a3, bv1);                          \
    MF(acc[2][2], a2, bv2); MF(acc[3][2], a3, bv2);                          \
    __builtin_amdgcn_s_setprio(0);                                           \
    a0 = LD8(Lb + aBase + 2048);                                             \
    a1 = LD8(Lb + aBase + 2560);                                             \
    a2 = LD8(Lb + aBase + 3072);                                             \
    a3 = LD8(Lb + aBase + 3584);                                             \
    if (DO_STAGE) STAGE_B((t) + 3)                                           \
    __builtin_amdgcn_s_setprio(1);                                           \
    MF(acc[4][0], a0, bv0); MF(acc[5][0], a1, bv0);                          \
    MF(acc[4][1], a0, bv1); MF(acc[5][1], a1, bv1);                          \
    MF(acc[4][2], a0, bv2); MF(acc[5][2], a1, bv2);                          \
    MF(acc[6][0], a2, bv0); MF(acc[7][0], a3, bv0);                          \
    MF(acc[6][1], a2, bv1); MF(acc[7][1], a3, bv1);                          \
    MF(acc[6][2], a2, bv2); MF(acc[7][2], a3, bv2);                          \
    __builtin_amdgcn_s_setprio(0);                                           \
    __builtin_amdgcn_sched_barrier(0);                                       \
    if (wid < 6) { asm volatile("s_waitcnt vmcnt(" #VM6 ")" ::: "memory"); } \
    else         { asm volatile("s_waitcnt vmcnt(" #VM2 ")" ::: "memory"); } \
    __builtin_amdgcn_s_barrier();                                            \
    __builtin_amdgcn_sched_barrier(0); }

#pragma unroll 1
  for (int t = 0; t < 29; ++t) K_TILE(t, 1, 8, 4)
  K_TILE(29, 0, 4, 2)
  K_TILE(30, 0, 0, 0)
  K_TILE(31, 0, 0, 0)

  const int crow = bm + wm * 128 + (lane >> 4) * 4;
  const int ccol = bn + wn * 48 + (lane & 15);
#pragma unroll
  for (int m = 0; m < 8; ++m)
#pragma unroll
    for (int n = 0; n < 3; ++n) {
      const int col = ccol + n * 16;
      const float bb = bias[col];
#pragma unroll
      for (int j = 0; j < 4; ++j)
        C[(size_t)(crow + m * 16 + j) * 3072 + col] = f2bf(acc[m][n][j] + bb);
    }
#undef K_TILE
#undef STAGE_A
#undef STAGE_B
}

// ---------------- GEMM2: out = gh @ W2s^T + bias2 (fp32 out), pipelined ----------------
// M=4096 N=1024 K=1024. BM=64 BN=128 BK=32, 256 thr (4 waves: 2M x 2N),
// grid (64,8) = 512 blocks = 2/CU (LDS 48KB). dualB: second W2s/bias2 copy
// for rows >= 2048 (batch 1).
__global__ __launch_bounds__(256, 2) void gemm2_pipe(const ushort_t* __restrict__ A,
                                                     const ushort_t* __restrict__ B,
                                                     const float* __restrict__ bias,
                                                     float* __restrict__ C) {
  __shared__ __align__(16) ushort_t lds[4 * 6144];   // [buf][A:2048 | B:4096] ushorts
  const int tid = threadIdx.x;
  const int wid = tid >> 6, lane = tid & 63;
  const int bm = blockIdx.x * 64, bn = blockIdx.y * 128;
  if (bm >= 2048) { B += (size_t)1024 * 1024; bias += 1024; }
  const int wm = wid >> 1, wn = wid & 1;

  const int srow = lane >> 2;
  const int scol = ((lane & 3) ^ ((lane >> 3) & 3)) * 8;
  const ushort_t* gA  = A + (size_t)(bm + wid * 16 + srow) * 1024 + scol;
  const ushort_t* gB0 = B + (size_t)(bn + wid * 16 + srow) * 1024 + scol;
  const ushort_t* gB1 = B + (size_t)(bn + (4 + wid) * 16 + srow) * 1024 + scol;

  const int lf = lane & 15, kf = lane >> 4;
  const int flip = ((lane >> 1) & 3) << 4;
  const int aBase = (((wm * 32 + lf) * 64 + kf * 16) ^ flip) >> 1;
  const int bBase = ((((wn * 64 + lf) * 64 + kf * 16) ^ flip) >> 1) + 2048;

  f32x4 acc[2][4] = {};

#define STAGE2(t)                                                            \
  { ushort_t* d = lds + (((t) & 3) * 6144);                                  \
    GLDS16(gA + (t) * 32, d + wid * 512);                                    \
    GLDS16(gB0 + (t) * 32, d + 2048 + wid * 512);                            \
    GLDS16(gB1 + (t) * 32, d + 2048 + (4 + wid) * 512); }

  STAGE2(0) STAGE2(1) STAGE2(2)
  asm volatile("s_waitcnt vmcnt(6)" ::: "memory");
  __builtin_amdgcn_s_barrier();
  __builtin_amdgcn_sched_barrier(0);

#define K_TILE2(t, DO_STAGE, VM)                                             \
  { const ushort_t* Lb = lds + (((t) & 3) * 6144);                           \
    short8 bv0 = LD8(Lb + bBase);                                            \
    short8 bv1 = LD8(Lb + bBase + 512);                                      \
    short8 bv2 = LD8(Lb + bBase + 1024);                                     \
    short8 bv3 = LD8(Lb + bBase + 1536);                                     \
    short8 a0 = LD8(Lb + aBase);                                             \
    short8 a1 = LD8(Lb + aBase + 512);                                       \
    if (DO_STAGE) STAGE2((t) + 3)                                            \
    __builtin_amdgcn_s_setprio(1);                                           \
    MF(acc[0][0], a0, bv0); MF(acc[1][0], a1, bv0);                          \
    MF(acc[0][1], a0, bv1); MF(acc[1][1], a1, bv1);                          \
    MF(acc[0][2], a0, bv2); MF(acc[1][2], a1, bv2);                          \
    MF(acc[0][3], a0, bv3); MF(acc[1][3], a1, bv3);                          \
    __builtin_amdgcn_s_setprio(0);                                           \
    __builtin_amdgcn_sched_barrier(0);                                       \
    asm volatile("s_waitcnt vmcnt(" #VM ")" ::: "memory");                   \
    __builtin_amdgcn_s_barrier();                                            \
    __builtin_amdgcn_sched_barrier(0); }

#pragma unroll 1
  for (int t = 0; t < 29; ++t) K_TILE2(t, 1, 6)
  K_TILE2(29, 0, 3)
  K_TILE2(30, 0, 0)
  K_TILE2(31, 0, 0)

  const int crow = bm + wm * 32 + (lane >> 4) * 4;
  const int ccol = bn + wn * 64 + lf;
#pragma unroll
  for (int m = 0; m < 2; ++m)
#pragma unroll
    for (int n = 0; n < 4; ++n) {
      const int col = ccol + n * 16;
      const float bb = bias[col];
#pragma unroll
      for (int j = 0; j < 4; ++j)
        C[(size_t)(crow + m * 16 + j) * 1024 + col] = acc[m][n][j] + bb;
    }
#undef K_TILE2
#undef STAGE2
}

// ---------------- partial KV = K^T V per (b,h,chunk=256 rows) ----------------
// grid = 64 bh * 8 chunks = 512 blocks (2/CU). 4 sequential 64-row LDS slabs.
__global__ __launch_bounds__(256) void kv_partial(const ushort_t* __restrict__ qkvb,
                                                  float* __restrict__ KVp) {
  __shared__ float kt[2048], vt[2048];
  const int blk = blockIdx.x;
  const int bh = blk >> 3;
  const int ch = blk & 7;
  const int b = bh >> 5, h = bh & 31;
  const int tid = threadIdx.x;
  const int r = tid >> 2, cg = (tid & 3) * 8;
  const int d = tid & 31, eg = tid >> 5;
  float kv[4] = {0.f, 0.f, 0.f, 0.f};
  for (int slab = 0; slab < 4; ++slab) {
    const ushort_t* kp = qkvb +
        (size_t)(b * SS + ch * 256 + slab * 64 + r) * 3072 + 1024 + h * 32 + cg;
    const short8 k8 = LD8(kp);
    const short8 v8 = LD8(kp + 1024);
    if (slab) __syncthreads();      // protect prior slab's reads
#pragma unroll
    for (int i = 0; i < 8; ++i) {
      kt[r * 32 + cg + i] = bf2f(k8[i]);
      vt[r * 32 + cg + i] = bf2f(v8[i]);
    }
    __syncthreads();
#pragma unroll 4
    for (int ss = 0; ss < 64; ++ss) {
      const float vv = vt[ss * 32 + d];
#pragma unroll
      for (int i = 0; i < 4; ++i)
        kv[i] += kt[ss * 32 + eg * 4 + i] * vv;
    }
  }
  float* o = KVp + ((size_t)bh * 8 + ch) * 1024 + (eg * 4) * 32 + d;
#pragma unroll
  for (int i = 0; i < 4; ++i) o[i * 32] = kv[i];
}

// ---------------- reduce 8 partials -> KV per (b,h) ----------------
__global__ __launch_bounds__(256) void kv_reduce(const float* __restrict__ KVp,
                                                 float* __restrict__ KV) {
  const int bh = blockIdx.x;          // 64 blocks
  const int tid = threadIdx.x;        // 256 threads * 4 elems = 1024
  const float* base = KVp + (size_t)bh * 8192 + tid * 4;
  float4 s = make_float4(0.f, 0.f, 0.f, 0.f);
  for (int c = 0; c < 8; ++c) {
    const float4 v = *(const float4*)(base + c * 1024);
    s.x += v.x; s.y += v.y; s.z += v.z; s.w += v.w;
  }
  *(float4*)&KV[(size_t)bh * 1024 + tid * 4] = s;
}

// ---------------- ctx = Q @ KV (bf16 out), plus partial (sum, sumsq) ----------------
__global__ __launch_bounds__(256) void ctx_kernel(const ushort_t* __restrict__ qkvb,
                                                  const float* __restrict__ KV,
                                                  ushort_t* __restrict__ ctxb,
                                                  float2* __restrict__ partials) {
  __shared__ float kvs[1024];
  __shared__ float red[8];
  const int blk = blockIdx.x;
  const int bh = blk >> 3, tt = blk & 7;
  const int b = bh >> 5, h = bh & 31;
  const int tid = threadIdx.x;
  for (int i = tid; i < 1024; i += 256) kvs[i] = KV[(size_t)bh * 1024 + i];
  __syncthreads();
  const int t = tt * 256 + tid;
  const ushort_t* qrow = qkvb + ((size_t)(b * SS + t)) * 3072 + h * 32;
  float q[32];
#pragma unroll
  for (int g = 0; g < 4; ++g) {
    const short8 qv = LD8(qrow + g * 8);
#pragma unroll
    for (int i = 0; i < 8; ++i) q[g * 8 + i] = bf2f(qv[i]);
  }
  float o[32];
#pragma unroll
  for (int d = 0; d < 32; ++d) o[d] = 0.f;
#pragma unroll
  for (int e = 0; e < 32; ++e) {
    const float qe = q[e];
    const float* kr = &kvs[e * 32];
#pragma unroll
    for (int d = 0; d < 32; ++d) o[d] += qe * kr[d];
  }
  float sum = 0.f, sq = 0.f;
#pragma unroll
  for (int d = 0; d < 32; ++d) { sum += o[d]; sq += o[d] * o[d]; }
  ushort_t* crow = ctxb + ((size_t)(b * SS + t)) * 1024 + h * 32;
#pragma unroll
  for (int g = 0; g < 4; ++g) {
    short8 ov;
#pragma unroll
    for (int i = 0; i < 8; ++i) ov[i] = (short)f2bf(o[g * 8 + i]);
    *(short8*)(crow + g * 8) = ov;
  }
  // deterministic block reduction (fixed shuffle tree, no float atomics)
#pragma unroll
  for (int off = 32; off > 0; off >>= 1) {
    sum += __shfl_down(sum, off);
    sq  += __shfl_down(sq, off);
  }
  const int wave = tid >> 6, lane = tid & 63;
  if (lane == 0) { red[wave * 2] = sum; red[wave * 2 + 1] = sq; }
  __syncthreads();
  if (tid == 0) {
    const float s = red[0] + red[2] + red[4] + red[6];
    const float q2 = red[1] + red[3] + red[5] + red[7];
    partials[blk] = make_float2(s, q2);
  }
}

// ---------------- fold groupnorm into GEMM2 operands (stats integrated) ----------------
__global__ __launch_bounds__(256) void fold_kernel(const float* __restrict__ W2,
                                                   const float* __restrict__ b2,
                                                   const float* __restrict__ gw,
                                                   const float* __restrict__ gb,
                                                   const float2* __restrict__ partials,
                                                   ushort_t* __restrict__ W2s,
                                                   float* __restrict__ bias2) {
  __shared__ float sS[1024], sT[1024];
  __shared__ float sMean[32], sRstd[32];
  const int b = blockIdx.y;
  const int tid = threadIdx.x;
  if (tid < 32) {   // per-(b,h) stats from the 8 partials (redundant per block; 2KB)
    float s = 0.f, q = 0.f;
    for (int i = 0; i < 8; ++i) {
      const float2 p = partials[(b * 32 + tid) * 8 + i];
      s += p.x; q += p.y;
    }
    const float mean = s * (1.f / 65536.f);
    const float var = q * (1.f / 65536.f) - mean * mean;
    sMean[tid] = mean; sRstd[tid] = rsqrtf(var + EPS);
  }
  __syncthreads();
  {
    const int c0 = tid * 4;
    const float mean = sMean[c0 >> 5], rstd = sRstd[c0 >> 5];
    const float4 w = *(const float4*)&gw[c0];
    const float4 g = *(const float4*)&gb[c0];
    sS[c0]     = rstd * w.x;  sT[c0]     = g.x - mean * rstd * w.x;
    sS[c0 + 1] = rstd * w.y;  sT[c0 + 1] = g.y - mean * rstd * w.y;
    sS[c0 + 2] = rstd * w.z;  sT[c0 + 2] = g.z - mean * rstd * w.z;
    sS[c0 + 3] = rstd * w.w;  sT[c0 + 3] = g.w - mean * rstd * w.w;
  }
  __syncthreads();
  const int row = blockIdx.x * 16 + (tid >> 4);
  const int l16 = tid & 15;
  float part = 0.f;
  for (int k = 0; k < 16; ++k) {
    const int c = k * 64 + l16 * 4;
    const float4 w2v = *(const float4*)&W2[(size_t)row * 1024 + c];
    ushort4 o;
    o.x = f2bf(w2v.x * sS[c]);
    o.y = f2bf(w2v.y * sS[c + 1]);
    o.z = f2bf(w2v.z * sS[c + 2]);
    o.w = f2bf(w2v.w * sS[c + 3]);
    *(ushort4*)&W2s[(size_t)b * 1048576 + (size_t)row * 1024 + c] = o;
    part += w2v.x * sT[c] + w2v.y * sT[c + 1] + w2v.z * sT[c + 2] + w2v.w * sT[c + 3];
  }
#pragma unroll
  for (int off = 8; off > 0; off >>= 1) part += __shfl_down(part, off, 16);
  if (l16 == 0) bias2[b * 1024 + row] = b2[row] + part;
}

extern "C" void kernel_launch(void* const* d_in, const int* in_sizes, int n_in,
                              void* d_out, int out_size, void* d_ws, size_t ws_size,
                              hipStream_t stream) {
  const float* x  = (const float*)d_in[0];
  const float* w1 = (const float*)d_in[1];
  const float* b1 = (const float*)d_in[2];
  const float* gw = (const float*)d_in[3];
  const float* gb = (const float*)d_in[4];
  const float* w2 = (const float*)d_in[5];
  const float* b2 = (const float*)d_in[6];
  float* out = (float*)d_out;

  char* ws = (char*)d_ws;
  ushort_t* Xb    = (ushort_t*)(ws);                 // 8 MB (dead after gemm1)
  float*    KVp   = (float*)(ws);                    // 2 MB, reuses Xb region
  ushort_t* W1b   = (ushort_t*)(ws + 8388608);       // 6 MB
  ushort_t* qkvb  = (ushort_t*)(ws + 16777216);      // 24 MB bf16
  ushort_t* ctxb  = (ushort_t*)(ws + 41943040);      // 8 MB bf16
  ushort_t* W2s   = (ushort_t*)(ws + 50331648);      // 4 MB (2 batches x 2 MB)
  float*    bias2 = (float*)(ws + 54525952);         // 8 KB
  float*    KV    = (float*)(ws + 54534144);         // 256 KB
  float2*   partials = (float2*)(ws + 54796288);     // 4 KB

  // 1. convert x and W1 to bf16 (fused)
  f2b2_kernel<<<2048, 256, 0, stream>>>(x, Xb, ROWS * 1024 / 4, w1, W1b, 3072 * 1024 / 4);
  // 2. qkv = x @ Wqkv^T + b  (bf16 out) — pipelined counted-vmcnt GEMM
  gemm1_pipe<<<dim3(16, 16), 512, 0, stream>>>(Xb, W1b, b1, qkvb);
  // 3. KV[b,h] = K^T V, 2-stage deterministic (chunk=256: 2MB partials)
  kv_partial<<<512, 256, 0, stream>>>(qkvb, KVp);
  kv_reduce<<<64, 256, 0, stream>>>(KVp, KV);
  // 4. ctx = Q @ KV (bf16), with partial groupnorm stats
  ctx_kernel<<<512, 256, 0, stream>>>(qkvb, KV, ctxb, partials);
  // 5. fold groupnorm into GEMM2's B and bias (stats computed in-kernel)
  fold_kernel<<<dim3(64, 2), 256, 0, stream>>>(w2, b2, gw, gb, partials, W2s, bias2);
  // 6. out = gh @ (W2*s)^T + (b2 + W2*t) — pipelined counted-vmcnt GEMM
  gemm2_pipe<<<dim3(64, 8), 256, 0, stream>>>(ctxb, W2s, bias2, out);
}